// Round 2
// baseline (889.064 us; speedup 1.0000x reference)
//
#include <hip/hip_runtime.h>

// Quantizer: B=8, N=4096, D=64, K=8192
// probs = softmax(sim/T) over K;  z_q = probs @ codebook
// sim = l2norm(z) @ l2norm(emb)^T, sim in [-1,1] -> no online max needed.
// Round 2: K-split both GEMM passes (occupancy 25% -> ~100%); pass A partials
// combined via fp32 atomics; probs pass standalone with 2x16 col tiles.

#define M_TOTAL 32768   // B*N
#define KCODES  8192
#define DDIM    64
#define KSPLIT  4
#define KCHUNK  (KCODES / KSPLIT)   // 2048

typedef __attribute__((ext_vector_type(8))) short bf16x8;
typedef __attribute__((ext_vector_type(4))) short bf16x4;
typedef __attribute__((ext_vector_type(4))) float f32x4;

__device__ inline unsigned short f2bf(float x) {
  union { float f; unsigned u; } v; v.f = x;
  unsigned r = v.u + 0x7FFFu + ((v.u >> 16) & 1u);  // RNE
  return (unsigned short)(r >> 16);
}

// One wave per row: L2-normalize, emit bf16 (and optional transposed copy).
__global__ __launch_bounds__(256) void norm_rows_kernel(
    const float* __restrict__ in, unsigned short* __restrict__ out,
    unsigned short* __restrict__ outT, int nrows, int tstride) {
  int row = blockIdx.x * 4 + (threadIdx.x >> 6);
  int lane = threadIdx.x & 63;
  if (row >= nrows) return;
  size_t idx = (size_t)row * DDIM + lane;
  float x = in[idx];
  float s = x * x;
  s += __shfl_xor(s, 1);  s += __shfl_xor(s, 2);  s += __shfl_xor(s, 4);
  s += __shfl_xor(s, 8);  s += __shfl_xor(s, 16); s += __shfl_xor(s, 32);
  float scale = 1.0f / fmaxf(sqrtf(s), 1e-12f);
  unsigned short b = f2bf(x * scale);
  out[idx] = b;
  if (outT) outT[(size_t)lane * tstride + row] = b;
}

// Pass A, K-split: per wave 16 rows x KCHUNK codes -> partial rowsum + partial
// U = sum(e * cb), combined with fp32 atomics into zeroed buffers.
__global__ __launch_bounds__(256) void passA_kernel(
    const unsigned short* __restrict__ Zn,   // [32768][64] bf16
    const unsigned short* __restrict__ Cb,   // [8192][64]  bf16
    const unsigned short* __restrict__ CbT,  // [64][8192]  bf16
    const float* __restrict__ tptr,
    float* __restrict__ U,                   // [32768][64] f32 (zeroed)
    float* __restrict__ rsbuf) {             // [32768]     f32 (zeroed)
  __shared__ unsigned short etile[4][16 * 56];  // 112B rows: 2-way alias only
  const int tid = threadIdx.x;
  const int w  = tid >> 6;
  const int l  = tid & 63;
  const int g  = l >> 4;
  const int ml = l & 15;
  const int rb = blockIdx.x & 511;
  const int ks = blockIdx.x >> 9;
  const int m_base = rb * 64 + w * 16;
  const int k0 = ks * KCHUNK;
  const float T  = tptr[0];
  const float sc = 1.4426950408889634f / T;  // log2(e)/T

  const bf16x8* znrow = (const bf16x8*)(Zn + (size_t)(m_base + ml) * DDIM);
  const bf16x8 zn0 = znrow[g];
  const bf16x8 zn1 = znrow[4 + g];

  const f32x4 zero = {0.f, 0.f, 0.f, 0.f};
  f32x4 uacc[4] = {zero, zero, zero, zero};  // U^T[d=ds*16+g*4+r][m=ml]
  float rs = 0.f;

  for (int kc = k0; kc < k0 + KCHUNK; kc += 32) {
#pragma unroll
    for (int cs = 0; cs < 2; ++cs) {
      const bf16x8* cbrow = (const bf16x8*)(Cb + (size_t)(kc + cs * 16 + ml) * DDIM);
      f32x4 acc = __builtin_amdgcn_mfma_f32_16x16x32_bf16(cbrow[g], zn0, zero, 0, 0, 0);
      acc = __builtin_amdgcn_mfma_f32_16x16x32_bf16(cbrow[4 + g], zn1, acc, 0, 0, 0);
      bf16x4 ep;
#pragma unroll
      for (int r = 0; r < 4; ++r) {
        float e = exp2f((acc[r] - 1.0f) * sc);  // exp((sim-1)/T) <= 1
        rs += e;
        ep[r] = (short)f2bf(e);
      }
      *(bf16x4*)&etile[w][ml * 56 + cs * 16 + g * 4] = ep;
    }
    asm volatile("s_waitcnt lgkmcnt(0)" ::: "memory");  // same-wave LDS dep
    const bf16x8 ef = *(const bf16x8*)&etile[w][ml * 56 + g * 8];
#pragma unroll
    for (int ds = 0; ds < 4; ++ds) {
      const bf16x8 ct = *(const bf16x8*)(CbT + (size_t)(ds * 16 + ml) * KCODES + kc + g * 8);
      uacc[ds] = __builtin_amdgcn_mfma_f32_16x16x32_bf16(ct, ef, uacc[ds], 0, 0, 0);
    }
  }

  // partial rowsum for row m_base+ml
  rs += __shfl_xor(rs, 16);
  rs += __shfl_xor(rs, 32);
  if (g == 0) atomicAdd(&rsbuf[m_base + ml], rs);

  float* urow = U + (size_t)(m_base + ml) * DDIM;
#pragma unroll
  for (int ds = 0; ds < 4; ++ds)
#pragma unroll
    for (int r = 0; r < 4; ++r)
      atomicAdd(&urow[ds * 16 + g * 4 + r], uacc[ds][r]);
}

// z_q = U / rs  (elementwise, vec4)
__global__ __launch_bounds__(256) void zq_kernel(
    const float* __restrict__ U, const float* __restrict__ rsbuf,
    float* __restrict__ zq) {
  int i = (blockIdx.x * 256 + threadIdx.x);      // one f32x4 per thread
  f32x4 u = *(const f32x4*)(U + (size_t)i * 4);
  float inv = 1.0f / rsbuf[(i * 4) >> 6];
  f32x4 v = {u[0] * inv, u[1] * inv, u[2] * inv, u[3] * inv};
  *(f32x4*)(zq + (size_t)i * 4) = v;
}

// Pass B, K-split: probs = exp((sim-1)/T) / rs, coalesced f32x4 stores.
__global__ __launch_bounds__(256) void probs_kernel(
    const unsigned short* __restrict__ Zn,
    const unsigned short* __restrict__ Cb,
    const float* __restrict__ tptr,
    const float* __restrict__ rsbuf,
    float* __restrict__ probs) {
  const int tid = threadIdx.x;
  const int w  = tid >> 6;
  const int l  = tid & 63;
  const int g  = l >> 4;
  const int ml = l & 15;
  const int rb = blockIdx.x & 511;
  const int ks = blockIdx.x >> 9;
  const int m_base = rb * 64 + w * 16;
  const int k0 = ks * KCHUNK;
  const float T  = tptr[0];
  const float sc = 1.4426950408889634f / T;

  const bf16x8* znrow = (const bf16x8*)(Zn + (size_t)(m_base + ml) * DDIM);
  const bf16x8 zn0 = znrow[g];
  const bf16x8 zn1 = znrow[4 + g];
  const float inv = 1.0f / rsbuf[m_base + ml];
  const f32x4 zero = {0.f, 0.f, 0.f, 0.f};

  float* prow = probs + (size_t)(m_base + ml) * KCODES;
  for (int kc = k0; kc < k0 + KCHUNK; kc += 32) {
    const bf16x8* cb0 = (const bf16x8*)(Cb + (size_t)(kc + ml) * DDIM);
    const bf16x8* cb1 = (const bf16x8*)(Cb + (size_t)(kc + 16 + ml) * DDIM);
    f32x4 a0 = __builtin_amdgcn_mfma_f32_16x16x32_bf16(cb0[g], zn0, zero, 0, 0, 0);
    a0 = __builtin_amdgcn_mfma_f32_16x16x32_bf16(cb0[4 + g], zn1, a0, 0, 0, 0);
    f32x4 a1 = __builtin_amdgcn_mfma_f32_16x16x32_bf16(cb1[g], zn0, zero, 0, 0, 0);
    a1 = __builtin_amdgcn_mfma_f32_16x16x32_bf16(cb1[4 + g], zn1, a1, 0, 0, 0);
    f32x4 p0, p1;
#pragma unroll
    for (int r = 0; r < 4; ++r) {
      p0[r] = exp2f((a0[r] - 1.0f) * sc) * inv;
      p1[r] = exp2f((a1[r] - 1.0f) * sc) * inv;
    }
    *(f32x4*)(prow + kc + g * 4) = p0;          // rows get 128B contiguous
    *(f32x4*)(prow + kc + 16 + g * 4) = p1;     // across the two tiles
  }
}

extern "C" void kernel_launch(void* const* d_in, const int* in_sizes, int n_in,
                              void* d_out, int out_size, void* d_ws, size_t ws_size,
                              hipStream_t stream) {
  const float* z    = (const float*)d_in[0];
  const float* emb  = (const float*)d_in[1];
  const float* temp = (const float*)d_in[2];

  float* probs = (float*)d_out;
  float* zq    = probs + (size_t)M_TOTAL * KCODES;

  unsigned short* Zn  = (unsigned short*)d_ws;              // 4 MB
  unsigned short* Cb  = Zn + (size_t)M_TOTAL * DDIM;        // 1 MB
  unsigned short* CbT = Cb + (size_t)KCODES * DDIM;         // 1 MB
  float* U     = (float*)(CbT + (size_t)KCODES * DDIM);     // 8 MB
  float* rsbuf = U + (size_t)M_TOTAL * DDIM;                // 128 KB

  hipMemsetAsync(U, 0, ((size_t)M_TOTAL * DDIM + M_TOTAL) * sizeof(float), stream);
  norm_rows_kernel<<<M_TOTAL / 4, 256, 0, stream>>>(z, Zn, nullptr, M_TOTAL, 0);
  norm_rows_kernel<<<KCODES / 4, 256, 0, stream>>>(emb, Cb, CbT, KCODES, KCODES);
  passA_kernel<<<512 * KSPLIT, 256, 0, stream>>>(Zn, Cb, CbT, temp, U, rsbuf);
  zq_kernel<<<(M_TOTAL * DDIM / 4) / 256, 256, 0, stream>>>(U, rsbuf, zq);
  probs_kernel<<<512 * KSPLIT, 256, 0, stream>>>(Zn, Cb, temp, rsbuf, probs);
}